// Round 8
// baseline (330.420 us; speedup 1.0000x reference)
//
#include <hip/hip_runtime.h>
#include <stdint.h>

#define NH 16
#define DH 64
#define DM 1024
#define Bz 4
#define Sz 2048

typedef __bf16 bf16x8 __attribute__((ext_vector_type(8)));
typedef float f32x4 __attribute__((ext_vector_type(4)));

// async global(16B/lane) -> LDS (wave-uniform base + lane*16)
#define GLD_LDS16(gsrc, ldst)                                             \
    __builtin_amdgcn_global_load_lds(                                     \
        (const __attribute__((address_space(1))) void*)(gsrc),            \
        (__attribute__((address_space(3))) void*)(ldst), 16, 0, 0)

__device__ __forceinline__ unsigned short f2bf(float f) {
    unsigned u = __float_as_uint(f);
    u += 0x7FFFu + ((u >> 16) & 1u);          // RNE
    return (unsigned short)(u >> 16);
}
__device__ __forceinline__ float bf2f(unsigned short h) {
    return __uint_as_float(((unsigned)h) << 16);
}

// ---------------------------------------------------------------------------
// Dtype detection (f32 vs bf16 storage) — see R2/R3 notes. flag=1 => f32.
// ---------------------------------------------------------------------------
__global__ void detect_dtype(const unsigned short* __restrict__ xs,
                             int* __restrict__ flagp)
{
    const int t = threadIdx.x;          // 64 threads, 1 block
    int cnt = 0;
    for (int i = 0; i < 64; i++) {
        const unsigned short h = xs[(t * 64 + i) * 2];
        const int e = (h >> 7) & 0xFF;
        if (h != 0 && e >= 100 && e <= 130) cnt++;
    }
#pragma unroll
    for (int off = 32; off >= 1; off >>= 1)
        cnt += __shfl_xor(cnt, off);
    if (t == 0) *flagp = (cnt < 2048) ? 1 : 0;
}

// ---------------------------------------------------------------------------
// Canonicalize 9 tensors into bf16 workspace buffers.
// ---------------------------------------------------------------------------
__global__ __launch_bounds__(256) void convert_inputs(
    const void* s0, const void* s1, const void* s2, const void* s3,
    const void* s4, const void* s5, const void* s6, const void* s7,
    const void* s8,
    unsigned short* d0, unsigned short* d1, unsigned short* d2,
    unsigned short* d3, unsigned short* d4, unsigned short* d5,
    unsigned short* d6, unsigned short* d7, unsigned short* d8,
    const int* __restrict__ flagp)
{
    const void* s; unsigned short* d; int n;
    switch (blockIdx.y) {
        case 0: s = s0; d = d0; n = Bz * Sz * DM; break;   // x
        case 1: s = s1; d = d1; n = DM * DM; break;        // Wq
        case 2: s = s2; d = d2; n = DM * DM; break;        // Wk
        case 3: s = s3; d = d3; n = DM * DM; break;        // Wv
        case 4: s = s4; d = d4; n = DM * DM; break;        // Wo
        case 5: s = s5; d = d5; n = DM; break;             // bq
        case 6: s = s6; d = d6; n = DM; break;             // bk
        case 7: s = s7; d = d7; n = DM; break;             // bv
        default: s = s8; d = d8; n = DM; break;            // bo
    }
    const int flag   = *flagp;
    const int stride = gridDim.x * blockDim.x * 4;
    const int base   = (blockIdx.x * blockDim.x + threadIdx.x) * 4;
    if (flag) {
        const float* sf = (const float*)s;
        for (int i = base; i < n; i += stride) {
            const float4 v = *reinterpret_cast<const float4*>(&sf[i]);
            ushort2 a, b;
            a.x = f2bf(v.x); a.y = f2bf(v.y);
            b.x = f2bf(v.z); b.y = f2bf(v.w);
            *reinterpret_cast<ushort2*>(&d[i])     = a;
            *reinterpret_cast<ushort2*>(&d[i + 2]) = b;
        }
    } else {
        const unsigned short* sh = (const unsigned short*)s;
        for (int i = base; i < n; i += stride)
            *reinterpret_cast<uint2*>(&d[i]) = *reinterpret_cast<const uint2*>(&sh[i]);
    }
}

// ---------------------------------------------------------------------------
// QKV projection: C = X[8192,1024] @ W[1024,1024]^T + b, scattered to
// Q,K: [b*16+h][s][64]  and  Vt: [b*16+h][d][s]   (all bf16)
// grid: (24, 64). BK=32 ping-pong LDS dbuf (2x16KB = same 32KB as R7 ->
// occupancy unchanged): async global_load_lds for k+1 issues BEFORE compute
// on k, so the vmcnt(0)+barrier at iteration end covers a completed load.
// ---------------------------------------------------------------------------
__global__ __launch_bounds__(256) void gemm_qkv(
    const unsigned short* __restrict__ X,
    const unsigned short* __restrict__ Wq,
    const unsigned short* __restrict__ Wk,
    const unsigned short* __restrict__ Wv,
    const unsigned short* __restrict__ bq,
    const unsigned short* __restrict__ bk,
    const unsigned short* __restrict__ bv,
    unsigned short* __restrict__ Qb,
    unsigned short* __restrict__ Kb,
    unsigned short* __restrict__ Vtb)
{
    __shared__ __align__(16) unsigned short As[2][128 * 32];
    __shared__ __align__(16) unsigned short Bs[2][128 * 32];
    const int tid  = threadIdx.x;
    const int w    = tid >> 6, lane = tid & 63;
    const int quad = lane >> 4, l15 = lane & 15;
    const int wm   = (w & 1) * 64, wn = (w >> 1) * 64;
    const int bm   = blockIdx.y * 128;
    const int proj = blockIdx.x >> 3;
    const int bn   = (blockIdx.x & 7) * 128;

    const unsigned short* W      = proj == 0 ? Wq : (proj == 1 ? Wk : Wv);
    const unsigned short* bias_p = proj == 0 ? bq : (proj == 1 ? bk : bv);

    const int lrow = lane >> 2;           // 0..15
    const int lcol = (lane & 3) * 8;      // 0,8,16,24

    f32x4 acc[4][4];
    for (int i = 0; i < 4; i++)
        for (int j = 0; j < 4; j++)
            acc[i][j] = f32x4{0.f, 0.f, 0.f, 0.f};

    // prologue: stage kk=0 into buf 0
#pragma unroll
    for (int t = 0; t < 2; t++) {
        const int r = w * 32 + t * 16;
        GLD_LDS16(&X[(size_t)(bm + r + lrow) * DM + lcol], &As[0][r * 32]);
        GLD_LDS16(&W[(size_t)(bn + r + lrow) * DM + lcol], &Bs[0][r * 32]);
    }
    asm volatile("s_waitcnt vmcnt(0)" ::: "memory");
    __syncthreads();

    int p = 0;
    for (int kk = 0; kk < DM; kk += 32) {
        // async prefetch of next K-slab into the other buffer
        if (kk + 32 < DM) {
#pragma unroll
            for (int t = 0; t < 2; t++) {
                const int r = w * 32 + t * 16;
                GLD_LDS16(&X[(size_t)(bm + r + lrow) * DM + kk + 32 + lcol], &As[p ^ 1][r * 32]);
                GLD_LDS16(&W[(size_t)(bn + r + lrow) * DM + kk + 32 + lcol], &Bs[p ^ 1][r * 32]);
            }
        }

        bf16x8 af[4], bfr[4];
#pragma unroll
        for (int i = 0; i < 4; i++)
            af[i] = *reinterpret_cast<const bf16x8*>(&As[p][(wm + i * 16 + l15) * 32 + quad * 8]);
#pragma unroll
        for (int j = 0; j < 4; j++)
            bfr[j] = *reinterpret_cast<const bf16x8*>(&Bs[p][(wn + j * 16 + l15) * 32 + quad * 8]);
#pragma unroll
        for (int i = 0; i < 4; i++)
#pragma unroll
            for (int j = 0; j < 4; j++)
                acc[i][j] = __builtin_amdgcn_mfma_f32_16x16x32_bf16(af[i], bfr[j], acc[i][j], 0, 0, 0);

        asm volatile("s_waitcnt vmcnt(0)" ::: "memory");   // prefetch landed (overlapped)
        __syncthreads();                                    // + all reads of buf p done
        p ^= 1;
    }

    // epilogue: C layout row = quad*4+r, col = l15
    if (proj < 2) {
        unsigned short* dst = (proj == 0) ? Qb : Kb;
#pragma unroll
        for (int j = 0; j < 4; j++) {
            const int   e    = bn + wn + j * 16 + l15;   // 0..1023
            const int   h    = e >> 6, dd = e & 63;
            const float bias = bf2f(bias_p[e]);
#pragma unroll
            for (int i = 0; i < 4; i++) {
#pragma unroll
                for (int r = 0; r < 4; r++) {
                    const int m = bm + wm + i * 16 + quad * 4 + r;
                    const int b = m >> 11, s = m & 2047;
                    dst[((size_t)(b * NH + h) * Sz + s) * DH + dd] = f2bf(acc[i][j][r] + bias);
                }
            }
        }
    } else {
        // V transposed: 4 consecutive s per lane -> one uint2 (4 bf16) store
#pragma unroll
        for (int j = 0; j < 4; j++) {
            const int   e    = bn + wn + j * 16 + l15;
            const int   h    = e >> 6, dd = e & 63;
            const float bias = bf2f(bias_p[e]);
#pragma unroll
            for (int i = 0; i < 4; i++) {
                const int m0 = bm + wm + i * 16 + quad * 4;     // s-aligned to 4
                const int b  = m0 >> 11, s0 = m0 & 2047;
                const unsigned u0 = __float_as_uint(acc[i][j][0] + bias) + 0x8000u;
                const unsigned u1 = __float_as_uint(acc[i][j][1] + bias) + 0x8000u;
                const unsigned u2 = __float_as_uint(acc[i][j][2] + bias) + 0x8000u;
                const unsigned u3 = __float_as_uint(acc[i][j][3] + bias) + 0x8000u;
                uint2 pk;
                pk.x = __builtin_amdgcn_perm(u1, u0, 0x07060302u);
                pk.y = __builtin_amdgcn_perm(u3, u2, 0x07060302u);
                *reinterpret_cast<uint2*>(
                    &Vtb[((size_t)(b * NH + h) * DH + dd) * Sz + s0]) = pk;
            }
        }
    }
}

// ---------------------------------------------------------------------------
// Flash attention (causal), fixed-max softmax, S^T orientation.
// 8 waves x 16 q = 128 q per block; two passes over chunk pair (c, 15-c)
// -> uniform 34 staged kv-tiles/block (placement-proof, R7).
// R8: K/V staging register-prefetched one tile ahead (loads issue before
// compute of the current tile -> HBM/L2 latency overlapped).
// grid: (8, 64) = 512 blocks = 2/CU x 8 waves.
// ---------------------------------------------------------------------------
__global__ __launch_bounds__(512) void flash_attn(
    const unsigned short* __restrict__ Qb,    // [64][2048][64]
    const unsigned short* __restrict__ Kb,    // [64][2048][64]
    const unsigned short* __restrict__ Vtb,   // [64][64][2048]
    unsigned short* __restrict__ AOb)         // [4][2048][1024]
{
    __shared__ __align__(16) unsigned short Ks[64 * 72];    // [kv][d]
    __shared__ __align__(16) unsigned short Vs[64 * 72];    // [d][kv]
    __shared__ __align__(16) unsigned short Ps[128 * 72];   // [q][kv], wave-private rows

    const int tid  = threadIdx.x;
    const int w    = tid >> 6, lane = tid & 63;
    const int quad = lane >> 4, l15 = lane & 15;
    const int bh   = blockIdx.y;
    const int cA   = (int)(blockIdx.x & 7);

    const int srow = tid >> 3;            // 0..63  (512 threads)
    const int scc  = (tid & 7) * 8;       // 0..56
    const int hh = bh & 15, bb = bh >> 4;

    const unsigned short* Krow = &Kb[((size_t)bh * Sz + srow) * DH + scc];
    const unsigned short* Vrow = &Vtb[((size_t)bh * DH + srow) * Sz + scc];

    for (int pass = 0; pass < 2; pass++) {
        const int chunk = pass ? (15 - cA) : cA;
        const int qb = chunk * 128;
        const int qw = qb + w * 16;                  // wave's 16 q rows

        // Q fragment: B-operand layout (row=q=l15, k=quad*8+j)
        const size_t qbase = ((size_t)bh * Sz + qw + l15) * DH;
        const bf16x8 qf0 = *reinterpret_cast<const bf16x8*>(&Qb[qbase + quad * 8]);
        const bf16x8 qf1 = *reinterpret_cast<const bf16x8*>(&Qb[qbase + 32 + quad * 8]);

        f32x4 o[4];
#pragma unroll
        for (int jd = 0; jd < 4; jd++) o[jd] = f32x4{0.f, 0.f, 0.f, 0.f};
        float lsum = 0.f;

        const int n_kv = qb + 128;

        // prologue: load tile kb=0 into regs
        uint4 kreg = *reinterpret_cast<const uint4*>(&Krow[0]);
        uint4 vreg = *reinterpret_cast<const uint4*>(&Vrow[0]);

        for (int kb = 0; kb < n_kv; kb += 64) {
            __syncthreads();                      // prev tile fully consumed
            *reinterpret_cast<uint4*>(&Ks[srow * 72 + scc]) = kreg;
            *reinterpret_cast<uint4*>(&Vs[srow * 72 + scc]) = vreg;
            __syncthreads();                      // tile visible to all waves

            // register prefetch of next tile (latency hidden behind compute)
            if (kb + 64 < n_kv) {
                kreg = *reinterpret_cast<const uint4*>(&Krow[(size_t)(kb + 64) * DH]);
                vreg = *reinterpret_cast<const uint4*>(&Vrow[kb + 64]);
            }

            if (kb > qw + 15) continue;          // fully masked for this wave
            const bool need_mask = (kb + 64 > qw);

            // S^T = K·Q^T per 16-kv tile j; softmax; pack; Ps write
#pragma unroll
            for (int j = 0; j < 4; j++) {
                const bf16x8 kf0 = *reinterpret_cast<const bf16x8*>(&Ks[(j * 16 + l15) * 72 + quad * 8]);
                const bf16x8 kf1 = *reinterpret_cast<const bf16x8*>(&Ks[(j * 16 + l15) * 72 + 32 + quad * 8]);
                f32x4 st = f32x4{0.f, 0.f, 0.f, 0.f};
                st = __builtin_amdgcn_mfma_f32_16x16x32_bf16(kf0, qf0, st, 0, 0, 0);
                st = __builtin_amdgcn_mfma_f32_16x16x32_bf16(kf1, qf1, st, 0, 0, 0);
                // p = exp(S/8) = exp2(S * 0.125*log2(e)); causal mask via select
                const int qa = qw + l15;
                float p[4];
#pragma unroll
                for (int r = 0; r < 4; r++) {
                    float e = __builtin_amdgcn_exp2f(st[r] * 0.18033688011f);
                    if (need_mask) {
                        const int kv = kb + j * 16 + quad * 4 + r;
                        e = (kv <= qa) ? e : 0.f;
                    }
                    p[r] = e;
                }
                lsum += (p[0] + p[1]) + (p[2] + p[3]);
                const unsigned u0 = __float_as_uint(p[0]) + 0x8000u;
                const unsigned u1 = __float_as_uint(p[1]) + 0x8000u;
                const unsigned u2 = __float_as_uint(p[2]) + 0x8000u;
                const unsigned u3 = __float_as_uint(p[3]) + 0x8000u;
                const unsigned pk0 = __builtin_amdgcn_perm(u1, u0, 0x07060302u);
                const unsigned pk1 = __builtin_amdgcn_perm(u3, u2, 0x07060302u);
                const int prow = (w * 16 + l15) * 72 + j * 16 + quad * 4;
                *reinterpret_cast<unsigned*>(&Ps[prow])     = pk0;
                *reinterpret_cast<unsigned*>(&Ps[prow + 2]) = pk1;
            }

            // wave-private Ps rows: in-wave drain only, no barrier
            asm volatile("s_waitcnt lgkmcnt(0)" ::: "memory");

            const bf16x8 pf0 = *reinterpret_cast<const bf16x8*>(&Ps[(w * 16 + l15) * 72 + quad * 8]);
            const bf16x8 pf1 = *reinterpret_cast<const bf16x8*>(&Ps[(w * 16 + l15) * 72 + 32 + quad * 8]);
#pragma unroll
            for (int jd = 0; jd < 4; jd++) {
                const bf16x8 vf0 = *reinterpret_cast<const bf16x8*>(&Vs[(jd * 16 + l15) * 72 + quad * 8]);
                const bf16x8 vf1 = *reinterpret_cast<const bf16x8*>(&Vs[(jd * 16 + l15) * 72 + 32 + quad * 8]);
                o[jd] = __builtin_amdgcn_mfma_f32_16x16x32_bf16(pf0, vf0, o[jd], 0, 0, 0);
                o[jd] = __builtin_amdgcn_mfma_f32_16x16x32_bf16(pf1, vf1, o[jd], 0, 0, 0);
            }
        }

        // reduce lsum across quads (lane holds partial for q = qw + l15)
        lsum += __shfl_xor(lsum, 16);
        lsum += __shfl_xor(lsum, 32);

        // write AO[b][s][h*64+d]; o[jd][r] is q-row quad*4+r, col jd*16+l15
        float linv[4];
#pragma unroll
        for (int r = 0; r < 4; r++)
            linv[r] = 1.0f / __shfl(lsum, quad * 4 + r);
#pragma unroll
        for (int jd = 0; jd < 4; jd++) {
#pragma unroll
            for (int r = 0; r < 4; r++) {
                const int s = qw + quad * 4 + r;
                AOb[((size_t)(bb * Sz + s)) * DM + hh * DH + jd * 16 + l15] =
                    f2bf(o[jd][r] * linv[r]);
            }
        }
    }
}

// ---------------------------------------------------------------------------
// Output projection: out = AO[8192,1024] @ Wo[1024,1024]^T + bo
// Stores f32 or bf16 per the dtype flag.  grid: (8, 64). BK=32 ping-pong dbuf.
// ---------------------------------------------------------------------------
__global__ __launch_bounds__(256) void gemm_out(
    const unsigned short* __restrict__ A,
    const unsigned short* __restrict__ W,
    const unsigned short* __restrict__ bo,
    void* __restrict__ outv,
    const int* __restrict__ flagp)
{
    __shared__ __align__(16) unsigned short As[2][128 * 32];
    __shared__ __align__(16) unsigned short Bs[2][128 * 32];
    const int tid  = threadIdx.x;
    const int w    = tid >> 6, lane = tid & 63;
    const int quad = lane >> 4, l15 = lane & 15;
    const int wm   = (w & 1) * 64, wn = (w >> 1) * 64;
    const int bm   = blockIdx.y * 128;
    const int bn   = blockIdx.x * 128;

    const int lrow = lane >> 2;
    const int lcol = (lane & 3) * 8;

    f32x4 acc[4][4];
    for (int i = 0; i < 4; i++)
        for (int j = 0; j < 4; j++)
            acc[i][j] = f32x4{0.f, 0.f, 0.f, 0.f};

#pragma unroll
    for (int t = 0; t < 2; t++) {
        const int r = w * 32 + t * 16;
        GLD_LDS16(&A[(size_t)(bm + r + lrow) * DM + lcol], &As[0][r * 32]);
        GLD_LDS16(&W[(size_t)(bn + r + lrow) * DM + lcol], &Bs[0][r * 32]);
    }
    asm volatile("s_waitcnt vmcnt(0)" ::: "memory");
    __syncthreads();

    int p = 0;
    for (int kk = 0; kk < DM; kk += 32) {
        if (kk + 32 < DM) {
#pragma unroll
            for (int t = 0; t < 2; t++) {
                const int r = w * 32 + t * 16;
                GLD_LDS16(&A[(size_t)(bm + r + lrow) * DM + kk + 32 + lcol], &As[p ^ 1][r * 32]);
                GLD_LDS16(&W[(size_t)(bn + r + lrow) * DM + kk + 32 + lcol], &Bs[p ^ 1][r * 32]);
            }
        }

        bf16x8 af[4], bfr[4];
#pragma unroll
        for (int i = 0; i < 4; i++)
            af[i] = *reinterpret_cast<const bf16x8*>(&As[p][(wm + i * 16 + l15) * 32 + quad * 8]);
#pragma unroll
        for (int j = 0; j < 4; j++)
            bfr[j] = *reinterpret_cast<const bf16x8*>(&Bs[p][(wn + j * 16 + l15) * 32 + quad * 8]);
#pragma unroll
        for (int i = 0; i < 4; i++)
#pragma unroll
            for (int j = 0; j < 4; j++)
                acc[i][j] = __builtin_amdgcn_mfma_f32_16x16x32_bf16(af[i], bfr[j], acc[i][j], 0, 0, 0);

        asm volatile("s_waitcnt vmcnt(0)" ::: "memory");
        __syncthreads();
        p ^= 1;
    }

    const int flag = *flagp;
    float*          outf = (float*)outv;
    unsigned short* outh = (unsigned short*)outv;
#pragma unroll
    for (int j = 0; j < 4; j++) {
        const int   e    = bn + wn + j * 16 + l15;
        const float bias = bf2f(bo[e]);
#pragma unroll
        for (int i = 0; i < 4; i++) {
#pragma unroll
            for (int r = 0; r < 4; r++) {
                const int   m = bm + wm + i * 16 + quad * 4 + r;
                const float v = acc[i][j][r] + bias;
                if (flag) outf[(size_t)m * DM + e] = v;
                else      outh[(size_t)m * DM + e] = f2bf(v);
            }
        }
    }
}

// ---------------------------------------------------------------------------
extern "C" void kernel_launch(void* const* d_in, const int* in_sizes, int n_in,
                              void* d_out, int out_size, void* d_ws, size_t ws_size,
                              hipStream_t stream) {
    // Bind inputs by ELEMENT COUNT (dtype/mask-presence robust)
    const void* x = nullptr;
    const void* Wsrc[4] = {nullptr, nullptr, nullptr, nullptr};
    const void* bsrc[4] = {nullptr, nullptr, nullptr, nullptr};
    int nw = 0, nb = 0;
    for (int i = 0; i < n_in; i++) {
        const int sz = in_sizes[i];
        if (sz == Bz * Sz * DM)            { if (!x) x = d_in[i]; }
        else if (sz == DM * DM)            { if (nw < 4) Wsrc[nw++] = d_in[i]; }
        else if (sz == DM)                 { if (nb < 4) bsrc[nb++] = d_in[i]; }
    }

    char* wsb = (char*)d_ws;
    int*  flagp = (int*)wsb;
    unsigned short* Xc  = (unsigned short*)(wsb + 16);
    const size_t NX = (size_t)Bz * Sz * DM;       // 8,388,608
    const size_t NW = (size_t)DM * DM;            // 1,048,576
    unsigned short* Wc0 = Xc  + NX;
    unsigned short* Wc1 = Wc0 + NW;
    unsigned short* Wc2 = Wc1 + NW;
    unsigned short* Wc3 = Wc2 + NW;
    unsigned short* bc0 = Wc3 + NW;
    unsigned short* bc1 = bc0 + DM;
    unsigned short* bc2 = bc1 + DM;
    unsigned short* bc3 = bc2 + DM;
    unsigned short* Qb  = bc3 + DM;
    const size_t SZ = (size_t)Bz * NH * Sz * DH;  // 8,388,608
    unsigned short* Kb  = Qb  + SZ;
    unsigned short* Vtb = Kb  + SZ;
    unsigned short* AOb = Vtb + SZ;

    detect_dtype<<<1, 64, 0, stream>>>((const unsigned short*)x, flagp);
    convert_inputs<<<dim3(512, 9), 256, 0, stream>>>(
        x, Wsrc[0], Wsrc[1], Wsrc[2], Wsrc[3],
        bsrc[0], bsrc[1], bsrc[2], bsrc[3],
        Xc, Wc0, Wc1, Wc2, Wc3, bc0, bc1, bc2, bc3, flagp);

    gemm_qkv <<<dim3(24, 64), 256, 0, stream>>>(Xc, Wc0, Wc1, Wc2, bc0, bc1, bc2, Qb, Kb, Vtb);
    flash_attn<<<dim3(8, 64), 512, 0, stream>>>(Qb, Kb, Vtb, AOb);
    gemm_out <<<dim3(8, 64), 256, 0, stream>>>(AOb, Wc3, bc3, d_out, flagp);
}